// Round 1
// baseline (741.967 us; speedup 1.0000x reference)
//
#include <hip/hip_runtime.h>
#include <math.h>

// ---------------- CSR build (sort edges by dst) ----------------

__global__ void deg_init(int* deg, int N) {
    int i = blockIdx.x * blockDim.x + threadIdx.x;
    if (i < N) deg[i] = 1;                    // self-loop
}

__global__ void deg_count(const int* __restrict__ ei, int E, int* deg) {
    int i = blockIdx.x * blockDim.x + threadIdx.x;
    if (i < E) atomicAdd(&deg[ei[E + i]], 1); // dst row of edge_index
}

__global__ void scan_partial(const int* __restrict__ deg, int N, int* bsum) {
    __shared__ int sm[256];
    int t = threadIdx.x;
    int i = blockIdx.x * 256 + t;
    int v = (i < N) ? deg[i] : 0;
    sm[t] = v; __syncthreads();
    for (int o = 1; o < 256; o <<= 1) {
        int u = (t >= o) ? sm[t - o] : 0;
        __syncthreads();
        sm[t] += u;
        __syncthreads();
    }
    if (t == 255) bsum[blockIdx.x] = sm[255];
}

__global__ void scan_bsums(int* bsum, int nb) {
    __shared__ int sm[256];
    int t = threadIdx.x;
    int v = (t < nb) ? bsum[t] : 0;
    sm[t] = v; __syncthreads();
    for (int o = 1; o < 256; o <<= 1) {
        int u = (t >= o) ? sm[t - o] : 0;
        __syncthreads();
        sm[t] += u;
        __syncthreads();
    }
    if (t < nb) bsum[t] = sm[t] - v;          // exclusive
}

__global__ void scan_final(const int* __restrict__ deg, const int* __restrict__ bsum,
                           int N, int* offs, int* cursor) {
    __shared__ int sm[256];
    int t = threadIdx.x;
    int i = blockIdx.x * 256 + t;
    int v = (i < N) ? deg[i] : 0;
    sm[t] = v; __syncthreads();
    for (int o = 1; o < 256; o <<= 1) {
        int u = (t >= o) ? sm[t - o] : 0;
        __syncthreads();
        sm[t] += u;
        __syncthreads();
    }
    int incl = sm[t] + bsum[blockIdx.x];
    if (i < N) { offs[i + 1] = incl; cursor[i] = incl - v; }
    if (i == 0) offs[0] = 0;
}

__global__ void scatter_edges(const int* __restrict__ ei, int E, int N,
                              int* cursor, int* srcs) {
    int i = blockIdx.x * blockDim.x + threadIdx.x;
    if (i < E) {
        int s = ei[i];
        int d = ei[E + i];
        int pos = atomicAdd(&cursor[d], 1);
        srcs[pos] = s;
    } else if (i < E + N) {
        int nn = i - E;
        int pos = atomicAdd(&cursor[nn], 1);
        srcs[pos] = nn;                        // self-loop
    }
}

// ---------------- GEMM: Y[N,128] = X[N,128] @ W[128,128] (fp32) ----------------

__global__ __launch_bounds__(256, 2) void gemm_x128(const float* __restrict__ X,
                                                    const float* __restrict__ W,
                                                    float* __restrict__ Y, int N) {
    __shared__ float wl[128 * 128];
    __shared__ float xl[32 * 128];
    int t = threadIdx.x;
    {
        const float4* W4 = (const float4*)W;
        float4* wl4 = (float4*)wl;
#pragma unroll
        for (int i = 0; i < 16; i++) wl4[t + 256 * i] = W4[t + 256 * i];
    }
    int row0 = blockIdx.x * 32;
    int nrows = N - row0; if (nrows > 32) nrows = 32;
    {
        const float4* X4 = (const float4*)(X + (size_t)row0 * 128);
        float4* xl4 = (float4*)xl;
        for (int i = t; i < nrows * 32; i += 256) xl4[i] = X4[i];
    }
    __syncthreads();
    int c = t & 127;
    int rb = (t >> 7) * 16;
    float acc[16];
#pragma unroll
    for (int r = 0; r < 16; r++) acc[r] = 0.f;
#pragma unroll 4
    for (int k = 0; k < 128; k++) {
        float wv = wl[k * 128 + c];
#pragma unroll
        for (int r = 0; r < 16; r++) acc[r] += xl[(rb + r) * 128 + k] * wv;
    }
    for (int r = 0; r < 16; r++) {
        int row = row0 + rb + r;
        if (row < N) Y[(size_t)row * 128 + c] = acc[r];
    }
}

// ---------------- per-node attention logits ----------------

template <int H>
__global__ void alpha_k(const float* __restrict__ h, const float* __restrict__ a_s,
                        const float* __restrict__ a_d, float* __restrict__ asb,
                        float* __restrict__ adb, int N) {
    int i = blockIdx.x * blockDim.x + threadIdx.x;
    if (i >= N * H) return;
    const int C = 128 / H;
    int n = i / H, hh = i % H;
    const float* hp = h + (size_t)n * 128 + hh * C;
    float s = 0.f, d = 0.f;
#pragma unroll
    for (int c = 0; c < C; c++) {
        float hv = hp[c];
        s += hv * a_s[hh * C + c];
        d += hv * a_d[hh * C + c];
    }
    asb[i] = s;
    adb[i] = d;
}

// ---------------- segment softmax + aggregate, one block per dst ----------------

template <int H, bool RELU>
__global__ __launch_bounds__(128) void aggregate_k(const float* __restrict__ h,
                                                   const int* __restrict__ offs,
                                                   const int* __restrict__ srcs,
                                                   const float* __restrict__ asb,
                                                   const float* __restrict__ adb,
                                                   const float* __restrict__ bias,
                                                   float* __restrict__ out) {
    int n = blockIdx.x, t = threadIdx.x;
    const int SH = (H == 4) ? 5 : 7;   // channels-per-head shift: 32 or 128
    int ht = t >> SH;
    int beg = offs[n], end = offs[n + 1];
    float adn = adb[n * H + ht];

    float m = -1e30f;
    for (int j = beg; j < end; j++) {
        int s = srcs[j];
        float e = asb[s * H + ht] + adn;
        e = e > 0.f ? e : 0.2f * e;
        m = fmaxf(m, e);
    }
    float den = 0.f, acc = 0.f;
    for (int j = beg; j < end; j++) {
        int s = srcs[j];
        float e = asb[s * H + ht] + adn;
        e = e > 0.f ? e : 0.2f * e;
        float p = __expf(e - m);
        den += p;
        acc += p * h[(size_t)s * 128 + t];
    }
    float o = acc / (den + 1e-16f) + bias[t];
    if (RELU) o = fmaxf(o, 0.f);
    out[(size_t)n * 128 + t] = o;
}

// ---------------- launch ----------------

extern "C" void kernel_launch(void* const* d_in, const int* in_sizes, int n_in,
                              void* d_out, int out_size, void* d_ws, size_t ws_size,
                              hipStream_t stream) {
    const float* x   = (const float*)d_in[0];
    const int*   ei  = (const int*)d_in[1];
    const float* W1  = (const float*)d_in[2];
    const float* as1 = (const float*)d_in[3];
    const float* ad1 = (const float*)d_in[4];
    const float* b1  = (const float*)d_in[5];
    const float* W2  = (const float*)d_in[6];
    const float* as2 = (const float*)d_in[7];
    const float* ad2 = (const float*)d_in[8];
    const float* b2  = (const float*)d_in[9];
    const float* W3  = (const float*)d_in[10];
    const float* as3 = (const float*)d_in[11];
    const float* ad3 = (const float*)d_in[12];
    const float* b3  = (const float*)d_in[13];

    const int N = in_sizes[0] / 128;
    const int E = in_sizes[1] / 2;
    const int NB = (N + 255) / 256;

    char* w = (char*)d_ws;
    size_t woff = 0;
    auto alloc = [&](size_t bytes) -> void* {
        void* p = w + woff;
        woff = (woff + bytes + 255) & ~(size_t)255;
        return p;
    };
    int*   deg    = (int*)alloc((size_t)(N + 1) * 4);
    int*   offs   = (int*)alloc((size_t)(N + 1) * 4);
    int*   cursor = (int*)alloc((size_t)(N + 1) * 4);
    int*   bsum   = (int*)alloc((size_t)NB * 4);
    int*   srcs   = (int*)alloc((size_t)(E + N) * 4);
    float* asb    = (float*)alloc((size_t)N * 4 * 4);
    float* adb    = (float*)alloc((size_t)N * 4 * 4);
    float* hbuf   = (float*)alloc((size_t)N * 128 * 4);
    float* outf   = (float*)d_out;

    // CSR build
    deg_init<<<(N + 255) / 256, 256, 0, stream>>>(deg, N);
    deg_count<<<(E + 255) / 256, 256, 0, stream>>>(ei, E, deg);
    scan_partial<<<NB, 256, 0, stream>>>(deg, N, bsum);
    scan_bsums<<<1, 256, 0, stream>>>(bsum, NB);
    scan_final<<<NB, 256, 0, stream>>>(deg, bsum, N, offs, cursor);
    scatter_edges<<<(E + N + 255) / 256, 256, 0, stream>>>(ei, E, N, cursor, srcs);

    const int gb = (N + 31) / 32;

    // Layer 1: x -> hbuf -> out (relu)
    gemm_x128<<<gb, 256, 0, stream>>>(x, W1, hbuf, N);
    alpha_k<4><<<(N * 4 + 255) / 256, 256, 0, stream>>>(hbuf, as1, ad1, asb, adb, N);
    aggregate_k<4, true><<<N, 128, 0, stream>>>(hbuf, offs, srcs, asb, adb, b1, outf);

    // Layer 2: out -> hbuf -> out (relu)
    gemm_x128<<<gb, 256, 0, stream>>>(outf, W2, hbuf, N);
    alpha_k<4><<<(N * 4 + 255) / 256, 256, 0, stream>>>(hbuf, as2, ad2, asb, adb, N);
    aggregate_k<4, true><<<N, 128, 0, stream>>>(hbuf, offs, srcs, asb, adb, b2, outf);

    // Layer 3: out -> hbuf -> out (single head, no relu)
    gemm_x128<<<gb, 256, 0, stream>>>(outf, W3, hbuf, N);
    alpha_k<1><<<(N + 255) / 256, 256, 0, stream>>>(hbuf, as3, ad3, asb, adb, N);
    aggregate_k<1, false><<<N, 128, 0, stream>>>(hbuf, offs, srcs, asb, adb, b3, outf);
}

// Round 2
// 470.467 us; speedup vs baseline: 1.5771x; 1.5771x over previous
//
#include <hip/hip_runtime.h>
#include <math.h>

#define MAXD 512   // max staged degree (Poisson(16)+1, max over 50k nodes ~45; fallback path covers more)

// ---------------- CSR build (sort edges by dst) ----------------

__global__ void deg_init(int* deg, int N) {
    int i = blockIdx.x * blockDim.x + threadIdx.x;
    if (i < N) deg[i] = 1;                    // self-loop
}

__global__ void deg_count(const int* __restrict__ ei, int E, int* deg) {
    int i = blockIdx.x * blockDim.x + threadIdx.x;
    if (i < E) atomicAdd(&deg[ei[E + i]], 1); // dst row of edge_index
}

__global__ void scan_partial(const int* __restrict__ deg, int N, int* bsum) {
    __shared__ int sm[256];
    int t = threadIdx.x;
    int i = blockIdx.x * 256 + t;
    int v = (i < N) ? deg[i] : 0;
    sm[t] = v; __syncthreads();
    for (int o = 1; o < 256; o <<= 1) {
        int u = (t >= o) ? sm[t - o] : 0;
        __syncthreads();
        sm[t] += u;
        __syncthreads();
    }
    if (t == 255) bsum[blockIdx.x] = sm[255];
}

__global__ void scan_bsums(int* bsum, int nb) {
    __shared__ int sm[256];
    int t = threadIdx.x;
    int v = (t < nb) ? bsum[t] : 0;
    sm[t] = v; __syncthreads();
    for (int o = 1; o < 256; o <<= 1) {
        int u = (t >= o) ? sm[t - o] : 0;
        __syncthreads();
        sm[t] += u;
        __syncthreads();
    }
    if (t < nb) bsum[t] = sm[t] - v;          // exclusive
}

__global__ void scan_final(const int* __restrict__ deg, const int* __restrict__ bsum,
                           int N, int* offs, int* cursor) {
    __shared__ int sm[256];
    int t = threadIdx.x;
    int i = blockIdx.x * 256 + t;
    int v = (i < N) ? deg[i] : 0;
    sm[t] = v; __syncthreads();
    for (int o = 1; o < 256; o <<= 1) {
        int u = (t >= o) ? sm[t - o] : 0;
        __syncthreads();
        sm[t] += u;
        __syncthreads();
    }
    int incl = sm[t] + bsum[blockIdx.x];
    if (i < N) { offs[i + 1] = incl; cursor[i] = incl - v; }
    if (i == 0) offs[0] = 0;
}

__global__ void scatter_edges(const int* __restrict__ ei, int E, int N,
                              int* cursor, int* srcs) {
    int i = blockIdx.x * blockDim.x + threadIdx.x;
    if (i < E) {
        int s = ei[i];
        int d = ei[E + i];
        int pos = atomicAdd(&cursor[d], 1);
        srcs[pos] = s;
    } else if (i < E + N) {
        int nn = i - E;
        int pos = atomicAdd(&cursor[nn], 1);
        srcs[pos] = nn;                        // self-loop
    }
}

// ------- GEMM: Y[N,128] = X[N,128] @ W[128,128], fp32, 4x4 register tile -------

__global__ __launch_bounds__(256, 2) void gemm_rt(const float* __restrict__ X,
                                                  const float* __restrict__ W,
                                                  float* __restrict__ Y, int N) {
    __shared__ float wl[128 * 128];   // [k][c]
    __shared__ float xt[128 * 32];    // [k][r]  (transposed x-tile)
    int t = threadIdx.x;
    {
        const float4* W4 = (const float4*)W;
        float4* wl4 = (float4*)wl;
#pragma unroll
        for (int i = 0; i < 16; i++) wl4[t + 256 * i] = W4[t + 256 * i];
    }
    int row0 = blockIdx.x * 32;
    {
        int r = t & 31, kc = t >> 5;           // 32 rows x 8 k-chunks of 16
        int row = row0 + r;
        bool ok = row < N;
        const float4* src = (const float4*)(X + (size_t)row * 128 + kc * 16);
        float4 z; z.x = z.y = z.z = z.w = 0.f;
#pragma unroll
        for (int q = 0; q < 4; q++) {
            float4 v = ok ? src[q] : z;
            int k = kc * 16 + q * 4;
            xt[(k + 0) * 32 + r] = v.x;
            xt[(k + 1) * 32 + r] = v.y;
            xt[(k + 2) * 32 + r] = v.z;
            xt[(k + 3) * 32 + r] = v.w;
        }
    }
    __syncthreads();
    int cg = t & 31, rg = t >> 5;              // 32 col-groups x 8 row-groups, 4x4 each
    float acc[4][4];
#pragma unroll
    for (int i = 0; i < 4; i++)
#pragma unroll
        for (int j = 0; j < 4; j++) acc[i][j] = 0.f;
    const float4* xt4 = (const float4*)xt;     // [k][rg]
    const float4* wl4r = (const float4*)wl;    // [k][cg]
#pragma unroll 8
    for (int k = 0; k < 128; k++) {
        float4 xv = xt4[k * 8 + rg];
        float4 wv = wl4r[k * 32 + cg];
        acc[0][0] += xv.x * wv.x; acc[0][1] += xv.x * wv.y; acc[0][2] += xv.x * wv.z; acc[0][3] += xv.x * wv.w;
        acc[1][0] += xv.y * wv.x; acc[1][1] += xv.y * wv.y; acc[1][2] += xv.y * wv.z; acc[1][3] += xv.y * wv.w;
        acc[2][0] += xv.z * wv.x; acc[2][1] += xv.z * wv.y; acc[2][2] += xv.z * wv.z; acc[2][3] += xv.z * wv.w;
        acc[3][0] += xv.w * wv.x; acc[3][1] += xv.w * wv.y; acc[3][2] += xv.w * wv.z; acc[3][3] += xv.w * wv.w;
    }
#pragma unroll
    for (int i = 0; i < 4; i++) {
        int row = row0 + rg * 4 + i;
        if (row < N) {
            float4 o; o.x = acc[i][0]; o.y = acc[i][1]; o.z = acc[i][2]; o.w = acc[i][3];
            *(float4*)&Y[(size_t)row * 128 + cg * 4] = o;
        }
    }
}

// ---------------- per-node attention logits (vectorized) ----------------

template <int H>
__global__ void node_logits(const float* __restrict__ h, const float* __restrict__ a_s,
                            const float* __restrict__ a_d, float* __restrict__ asb,
                            float* __restrict__ adb, int N) {
    int i = blockIdx.x * blockDim.x + threadIdx.x;
    if (i >= N * H) return;
    const int C = 128 / H;
    int n = i / H, hh = i - n * H;
    const float4* hp  = (const float4*)(h + (size_t)n * 128 + hh * C);
    const float4* ap  = (const float4*)(a_s + hh * C);
    const float4* bp  = (const float4*)(a_d + hh * C);
    float s = 0.f, d = 0.f;
#pragma unroll
    for (int c = 0; c < C / 4; c++) {
        float4 hv = hp[c], av = ap[c], bv = bp[c];
        s += hv.x * av.x + hv.y * av.y + hv.z * av.z + hv.w * av.w;
        d += hv.x * bv.x + hv.y * bv.y + hv.z * bv.z + hv.w * bv.w;
    }
    asb[i] = s;
    adb[i] = d;
}

// ------- edge softmax: thread per (dst,head); writes unnormalized p + denom -------

__device__ __forceinline__ float lrelu(float v) { return v > 0.f ? v : 0.2f * v; }

template <int H>
__global__ void edge_softmax(const int* __restrict__ offs, const int* __restrict__ srcs,
                             const float* __restrict__ asb, const float* __restrict__ adb,
                             float* __restrict__ alpha, float* __restrict__ denom, int N) {
    int i = blockIdx.x * blockDim.x + threadIdx.x;
    if (i >= N * H) return;
    int n = i / H, ht = i - n * H;
    int beg = offs[n], end = offs[n + 1];
    float adn = adb[i];

    // pass 1: max of as over neighbors (leaky_relu is monotone)
    float mx = -1e30f;
    int j = beg;
    for (; j + 4 <= end; j += 4) {
        int s0 = srcs[j], s1 = srcs[j + 1], s2 = srcs[j + 2], s3 = srcs[j + 3];
        float v0 = asb[(size_t)s0 * H + ht], v1 = asb[(size_t)s1 * H + ht];
        float v2 = asb[(size_t)s2 * H + ht], v3 = asb[(size_t)s3 * H + ht];
        mx = fmaxf(mx, fmaxf(fmaxf(v0, v1), fmaxf(v2, v3)));
    }
    for (; j < end; j++) mx = fmaxf(mx, asb[(size_t)srcs[j] * H + ht]);
    float m = lrelu(mx + adn);

    // pass 2: p = exp(e - m), denom
    float den = 0.f;
    j = beg;
    for (; j + 4 <= end; j += 4) {
        int s0 = srcs[j], s1 = srcs[j + 1], s2 = srcs[j + 2], s3 = srcs[j + 3];
        float p0 = __expf(lrelu(asb[(size_t)s0 * H + ht] + adn) - m);
        float p1 = __expf(lrelu(asb[(size_t)s1 * H + ht] + adn) - m);
        float p2 = __expf(lrelu(asb[(size_t)s2 * H + ht] + adn) - m);
        float p3 = __expf(lrelu(asb[(size_t)s3 * H + ht] + adn) - m);
        den += p0 + p1 + p2 + p3;
        alpha[(size_t)j * H + ht]       = p0;
        alpha[(size_t)(j + 1) * H + ht] = p1;
        alpha[(size_t)(j + 2) * H + ht] = p2;
        alpha[(size_t)(j + 3) * H + ht] = p3;
    }
    for (; j < end; j++) {
        float p = __expf(lrelu(asb[(size_t)srcs[j] * H + ht] + adn) - m);
        den += p;
        alpha[(size_t)j * H + ht] = p;
    }
    denom[i] = den;
}

// ------- aggregation: one block per dst, single pass, LDS-staged indices, MLP-4 -------

template <int H, bool RELU>
__global__ __launch_bounds__(128) void aggregate3(const float* __restrict__ h,
                                                  const int* __restrict__ offs,
                                                  const int* __restrict__ srcs,
                                                  const float* __restrict__ alpha,
                                                  const float* __restrict__ denom,
                                                  const float* __restrict__ bias,
                                                  float* __restrict__ out) {
    __shared__ int   ssrc[MAXD];
    __shared__ float sal[MAXD * H];
    int n = blockIdx.x, t = threadIdx.x;
    int ht = (H == 4) ? (t >> 5) : 0;
    int beg = offs[n], end = offs[n + 1];
    int deg = end - beg;
    float acc = 0.f;

    if (deg <= MAXD) {
        for (int j = t; j < deg; j += 128) {
            ssrc[j] = srcs[beg + j];
            if (H == 4)
                *(float4*)&sal[j * 4] = *(const float4*)&alpha[(size_t)(beg + j) * 4];
            else
                sal[j] = alpha[beg + j];
        }
        __syncthreads();
        int j = 0;
        for (; j + 4 <= deg; j += 4) {
            int s0 = ssrc[j], s1 = ssrc[j + 1], s2 = ssrc[j + 2], s3 = ssrc[j + 3];
            float a0 = sal[j * H + ht], a1 = sal[(j + 1) * H + ht];
            float a2 = sal[(j + 2) * H + ht], a3 = sal[(j + 3) * H + ht];
            float h0 = h[(size_t)s0 * 128 + t];
            float h1 = h[(size_t)s1 * 128 + t];
            float h2 = h[(size_t)s2 * 128 + t];
            float h3 = h[(size_t)s3 * 128 + t];
            acc += a0 * h0; acc += a1 * h1; acc += a2 * h2; acc += a3 * h3;
        }
        for (; j < deg; j++)
            acc += sal[j * H + ht] * h[(size_t)ssrc[j] * 128 + t];
    } else {
        for (int j = beg; j < end; j++)
            acc += alpha[(size_t)j * H + ht] * h[(size_t)srcs[j] * 128 + t];
    }

    float o = acc / (denom[(size_t)n * H + ht] + 1e-16f) + bias[t];
    if (RELU) o = fmaxf(o, 0.f);
    out[(size_t)n * 128 + t] = o;
}

// ---------------- launch ----------------

extern "C" void kernel_launch(void* const* d_in, const int* in_sizes, int n_in,
                              void* d_out, int out_size, void* d_ws, size_t ws_size,
                              hipStream_t stream) {
    const float* x   = (const float*)d_in[0];
    const int*   ei  = (const int*)d_in[1];
    const float* W1  = (const float*)d_in[2];
    const float* as1 = (const float*)d_in[3];
    const float* ad1 = (const float*)d_in[4];
    const float* b1  = (const float*)d_in[5];
    const float* W2  = (const float*)d_in[6];
    const float* as2 = (const float*)d_in[7];
    const float* ad2 = (const float*)d_in[8];
    const float* b2  = (const float*)d_in[9];
    const float* W3  = (const float*)d_in[10];
    const float* as3 = (const float*)d_in[11];
    const float* ad3 = (const float*)d_in[12];
    const float* b3  = (const float*)d_in[13];

    const int N = in_sizes[0] / 128;
    const int E = in_sizes[1] / 2;
    const int NB = (N + 255) / 256;

    char* w = (char*)d_ws;
    size_t woff = 0;
    auto alloc = [&](size_t bytes) -> void* {
        void* p = w + woff;
        woff = (woff + bytes + 255) & ~(size_t)255;
        return p;
    };
    int*   deg    = (int*)alloc((size_t)(N + 1) * 4);
    int*   offs   = (int*)alloc((size_t)(N + 1) * 4);
    int*   cursor = (int*)alloc((size_t)(N + 1) * 4);
    int*   bsum   = (int*)alloc((size_t)NB * 4);
    int*   srcs   = (int*)alloc((size_t)(E + N) * 4);
    float* asb    = (float*)alloc((size_t)N * 4 * 4);
    float* adb    = (float*)alloc((size_t)N * 4 * 4);
    float* denom  = (float*)alloc((size_t)N * 4 * 4);
    float* alpha  = (float*)alloc((size_t)(E + N) * 4 * 4);
    float* hbuf   = (float*)alloc((size_t)N * 128 * 4);
    float* outf   = (float*)d_out;

    // CSR build
    deg_init<<<(N + 255) / 256, 256, 0, stream>>>(deg, N);
    deg_count<<<(E + 255) / 256, 256, 0, stream>>>(ei, E, deg);
    scan_partial<<<NB, 256, 0, stream>>>(deg, N, bsum);
    scan_bsums<<<1, 256, 0, stream>>>(bsum, NB);
    scan_final<<<NB, 256, 0, stream>>>(deg, bsum, N, offs, cursor);
    scatter_edges<<<(E + N + 255) / 256, 256, 0, stream>>>(ei, E, N, cursor, srcs);

    const int gb = (N + 31) / 32;

    // Layer 1: x -> hbuf -> out (relu)
    gemm_rt<<<gb, 256, 0, stream>>>(x, W1, hbuf, N);
    node_logits<4><<<(N * 4 + 255) / 256, 256, 0, stream>>>(hbuf, as1, ad1, asb, adb, N);
    edge_softmax<4><<<(N * 4 + 255) / 256, 256, 0, stream>>>(offs, srcs, asb, adb, alpha, denom, N);
    aggregate3<4, true><<<N, 128, 0, stream>>>(hbuf, offs, srcs, alpha, denom, b1, outf);

    // Layer 2: out -> hbuf -> out (relu)
    gemm_rt<<<gb, 256, 0, stream>>>(outf, W2, hbuf, N);
    node_logits<4><<<(N * 4 + 255) / 256, 256, 0, stream>>>(hbuf, as2, ad2, asb, adb, N);
    edge_softmax<4><<<(N * 4 + 255) / 256, 256, 0, stream>>>(offs, srcs, asb, adb, alpha, denom, N);
    aggregate3<4, true><<<N, 128, 0, stream>>>(hbuf, offs, srcs, alpha, denom, b2, outf);

    // Layer 3: out -> hbuf -> out (single head, no relu)
    gemm_rt<<<gb, 256, 0, stream>>>(outf, W3, hbuf, N);
    node_logits<1><<<(N + 255) / 256, 256, 0, stream>>>(hbuf, as3, ad3, asb, adb, N);
    edge_softmax<1><<<(N + 255) / 256, 256, 0, stream>>>(offs, srcs, asb, adb, alpha, denom, N);
    aggregate3<1, false><<<N, 128, 0, stream>>>(hbuf, offs, srcs, alpha, denom, b3, outf);
}

// Round 3
// 449.087 us; speedup vs baseline: 1.6522x; 1.0476x over previous
//
#include <hip/hip_runtime.h>
#include <hip/hip_bf16.h>
#include <math.h>

__device__ __forceinline__ float lrelu(float v) { return v > 0.f ? v : 0.2f * v; }

// monotone float <-> uint encoding for atomicMax on signed floats
__device__ __forceinline__ unsigned fenc(float f) {
    unsigned u = __float_as_uint(f);
    return (u & 0x80000000u) ? ~u : (u | 0x80000000u);
}
__device__ __forceinline__ float fdec(unsigned u) {
    return __uint_as_float((u & 0x80000000u) ? (u & 0x7FFFFFFFu) : ~u);
}
__device__ __forceinline__ unsigned short f2bf(float f) {
    union { __hip_bfloat16 b; unsigned short u; } cv;
    cv.b = __float2bfloat16(f);
    return cv.u;
}

// ---------------- CSR build (sort edges by dst) ----------------

__global__ void deg_init(int* deg, int N) {
    int i = blockIdx.x * blockDim.x + threadIdx.x;
    if (i < N) deg[i] = 1;                    // self-loop
}

__global__ void deg_count(const int* __restrict__ ei, int E, int* deg) {
    int i = blockIdx.x * blockDim.x + threadIdx.x;
    if (i < E) atomicAdd(&deg[ei[E + i]], 1);
}

__global__ void scan_partial(const int* __restrict__ deg, int N, int* bsum) {
    __shared__ int sm[256];
    int t = threadIdx.x;
    int i = blockIdx.x * 256 + t;
    int v = (i < N) ? deg[i] : 0;
    sm[t] = v; __syncthreads();
    for (int o = 1; o < 256; o <<= 1) {
        int u = (t >= o) ? sm[t - o] : 0;
        __syncthreads();
        sm[t] += u;
        __syncthreads();
    }
    if (t == 255) bsum[blockIdx.x] = sm[255];
}

__global__ void scan_bsums(int* bsum, int nb) {
    __shared__ int sm[256];
    int t = threadIdx.x;
    int v = (t < nb) ? bsum[t] : 0;
    sm[t] = v; __syncthreads();
    for (int o = 1; o < 256; o <<= 1) {
        int u = (t >= o) ? sm[t - o] : 0;
        __syncthreads();
        sm[t] += u;
        __syncthreads();
    }
    if (t < nb) bsum[t] = sm[t] - v;          // exclusive
}

__global__ void scan_final(const int* __restrict__ deg, const int* __restrict__ bsum,
                           int N, int* offs, int* cursor) {
    __shared__ int sm[256];
    int t = threadIdx.x;
    int i = blockIdx.x * 256 + t;
    int v = (i < N) ? deg[i] : 0;
    sm[t] = v; __syncthreads();
    for (int o = 1; o < 256; o <<= 1) {
        int u = (t >= o) ? sm[t - o] : 0;
        __syncthreads();
        sm[t] += u;
        __syncthreads();
    }
    int incl = sm[t] + bsum[blockIdx.x];
    if (i < N) { offs[i + 1] = incl; cursor[i] = incl - v; }
    if (i == 0) offs[0] = 0;
}

__global__ void scatter_edges(const int* __restrict__ ei, int E, int N,
                              int* cursor, int* srcs) {
    int i = blockIdx.x * blockDim.x + threadIdx.x;
    if (i < E) {
        int s = ei[i];
        int d = ei[E + i];
        int pos = atomicAdd(&cursor[d], 1);
        srcs[pos] = s;
    } else if (i < E + N) {
        int nn = i - E;
        int pos = atomicAdd(&cursor[nn], 1);
        srcs[pos] = nn;                        // self-loop
    }
}

// ------- GEMM + fused node logits: h=X@W (bf16 out), as/ad per (node,head) -------

template <int H>
__global__ __launch_bounds__(256, 2) void gemm_fused(const float* __restrict__ X,
                                                     const float* __restrict__ W,
                                                     const float* __restrict__ a_s,
                                                     const float* __restrict__ a_d,
                                                     unsigned short* __restrict__ hb,
                                                     float* __restrict__ asb,
                                                     float* __restrict__ adb,
                                                     unsigned* __restrict__ asMax,
                                                     int N) {
    __shared__ float wl[128 * 128];   // [k][c]
    __shared__ float xt[128 * 32];    // [k][r]
    int t = threadIdx.x;
    {
        const float4* W4 = (const float4*)W;
        float4* wl4 = (float4*)wl;
#pragma unroll
        for (int i = 0; i < 16; i++) wl4[t + 256 * i] = W4[t + 256 * i];
    }
    int row0 = blockIdx.x * 32;
    {
        int r = t & 31, kc = t >> 5;
        int row = row0 + r;
        bool ok = row < N;
        const float4* src = (const float4*)(X + (size_t)row * 128 + kc * 16);
        float4 z; z.x = z.y = z.z = z.w = 0.f;
#pragma unroll
        for (int q = 0; q < 4; q++) {
            float4 v = ok ? src[q] : z;
            int k = kc * 16 + q * 4;
            xt[(k + 0) * 32 + r] = v.x;
            xt[(k + 1) * 32 + r] = v.y;
            xt[(k + 2) * 32 + r] = v.z;
            xt[(k + 3) * 32 + r] = v.w;
        }
    }
    __syncthreads();
    int cg = t & 31, rg = t >> 5;
    float acc[4][4];
#pragma unroll
    for (int i = 0; i < 4; i++)
#pragma unroll
        for (int j = 0; j < 4; j++) acc[i][j] = 0.f;
    const float4* xt4  = (const float4*)xt;
    const float4* wl4r = (const float4*)wl;
#pragma unroll 8
    for (int k = 0; k < 128; k++) {
        float4 xv = xt4[k * 8 + rg];
        float4 wv = wl4r[k * 32 + cg];
        acc[0][0] += xv.x * wv.x; acc[0][1] += xv.x * wv.y; acc[0][2] += xv.x * wv.z; acc[0][3] += xv.x * wv.w;
        acc[1][0] += xv.y * wv.x; acc[1][1] += xv.y * wv.y; acc[1][2] += xv.y * wv.z; acc[1][3] += xv.y * wv.w;
        acc[2][0] += xv.z * wv.x; acc[2][1] += xv.z * wv.y; acc[2][2] += xv.z * wv.z; acc[2][3] += xv.z * wv.w;
        acc[3][0] += xv.w * wv.x; acc[3][1] += xv.w * wv.y; acc[3][2] += xv.w * wv.z; acc[3][3] += xv.w * wv.w;
    }
    // write bf16 h
#pragma unroll
    for (int i = 0; i < 4; i++) {
        int row = row0 + rg * 4 + i;
        if (row < N) {
            ushort4 o;
            o.x = f2bf(acc[i][0]); o.y = f2bf(acc[i][1]);
            o.z = f2bf(acc[i][2]); o.w = f2bf(acc[i][3]);
            *(ushort4*)&hb[(size_t)row * 128 + cg * 4] = o;
        }
    }
    // fused per-(row,head) logits: reduce partial dots across lanes of same head
    constexpr int C = 128 / H;
    int head = (H == 4) ? (cg >> 3) : 0;
    int cidx = (H == 4) ? ((cg & 7) * 4) : (cg * 4);
    float4 as4 = *(const float4*)&a_s[head * C + cidx];
    float4 ad4 = *(const float4*)&a_d[head * C + cidx];
    float ps[4], pd[4];
#pragma unroll
    for (int i = 0; i < 4; i++) {
        ps[i] = acc[i][0] * as4.x + acc[i][1] * as4.y + acc[i][2] * as4.z + acc[i][3] * as4.w;
        pd[i] = acc[i][0] * ad4.x + acc[i][1] * ad4.y + acc[i][2] * ad4.z + acc[i][3] * ad4.w;
    }
    constexpr int RED = (H == 4) ? 8 : 32;
    for (int o = 1; o < RED; o <<= 1) {
#pragma unroll
        for (int i = 0; i < 4; i++) {
            ps[i] += __shfl_xor(ps[i], o);
            pd[i] += __shfl_xor(pd[i], o);
        }
    }
    if ((t & (RED - 1)) == 0) {
#pragma unroll
        for (int i = 0; i < 4; i++) {
            int row = row0 + rg * 4 + i;
            if (row < N) {
                asb[(size_t)row * H + head] = ps[i];
                adb[(size_t)row * H + head] = pd[i];
                asMax[(size_t)row * H + head] = fenc(ps[i]);   // self-loop seed
            }
        }
    }
}

// ------- edge-parallel segment max: atomicMax of encoded src logits per (dst,head) -------

template <int H>
__global__ void edge_max(const int* __restrict__ ei, int E,
                         const float* __restrict__ asb, unsigned* __restrict__ asMax) {
    int i = blockIdx.x * blockDim.x + threadIdx.x;
    if (i >= E * H) return;
    int e, ht;
    if (H == 4) { e = i >> 2; ht = i & 3; } else { e = i; ht = 0; }
    int s = ei[e];
    int d = ei[E + e];
    atomicMax(&asMax[(size_t)d * H + ht], fenc(asb[(size_t)s * H + ht]));
}

// ------- aggregation: one wave per dst node, inline softmax, bf16 h gather -------

template <int H, bool RELU>
__global__ __launch_bounds__(256) void aggregate4(const unsigned short* __restrict__ hb,
                                                  const int* __restrict__ offs,
                                                  const int* __restrict__ srcs,
                                                  const float* __restrict__ asb,
                                                  const float* __restrict__ adb,
                                                  const unsigned* __restrict__ asMax,
                                                  const float* __restrict__ bias,
                                                  float* __restrict__ out, int N) {
    int n = (blockIdx.x * 256 + threadIdx.x) >> 6;   // wave id = node
    if (n >= N) return;
    int lane = threadIdx.x & 63;
    int c = lane * 2;                                 // 2 channels per lane
    int ht = (H == 4) ? (lane >> 4) : 0;
    float adn = adb[(size_t)n * H + ht];
    float m = lrelu(fdec(asMax[(size_t)n * H + ht]) + adn);
    int beg = offs[n], end = offs[n + 1];
    float accx = 0.f, accy = 0.f, den = 0.f;
    int j = beg;
    for (; j + 4 <= end; j += 4) {
        int s0 = srcs[j], s1 = srcs[j + 1], s2 = srcs[j + 2], s3 = srcs[j + 3];
        unsigned u0 = *(const unsigned*)&hb[(size_t)s0 * 128 + c];
        unsigned u1 = *(const unsigned*)&hb[(size_t)s1 * 128 + c];
        unsigned u2 = *(const unsigned*)&hb[(size_t)s2 * 128 + c];
        unsigned u3 = *(const unsigned*)&hb[(size_t)s3 * 128 + c];
        float e0 = asb[(size_t)s0 * H + ht], e1 = asb[(size_t)s1 * H + ht];
        float e2 = asb[(size_t)s2 * H + ht], e3 = asb[(size_t)s3 * H + ht];
        float p0 = __expf(lrelu(e0 + adn) - m);
        float p1 = __expf(lrelu(e1 + adn) - m);
        float p2 = __expf(lrelu(e2 + adn) - m);
        float p3 = __expf(lrelu(e3 + adn) - m);
        accx += p0 * __uint_as_float(u0 << 16);
        accy += p0 * __uint_as_float(u0 & 0xFFFF0000u);
        accx += p1 * __uint_as_float(u1 << 16);
        accy += p1 * __uint_as_float(u1 & 0xFFFF0000u);
        accx += p2 * __uint_as_float(u2 << 16);
        accy += p2 * __uint_as_float(u2 & 0xFFFF0000u);
        accx += p3 * __uint_as_float(u3 << 16);
        accy += p3 * __uint_as_float(u3 & 0xFFFF0000u);
        den += p0 + p1 + p2 + p3;
    }
    for (; j < end; j++) {
        int s = srcs[j];
        unsigned u = *(const unsigned*)&hb[(size_t)s * 128 + c];
        float p = __expf(lrelu(asb[(size_t)s * H + ht] + adn) - m);
        accx += p * __uint_as_float(u << 16);
        accy += p * __uint_as_float(u & 0xFFFF0000u);
        den += p;
    }
    float inv = 1.f / (den + 1e-16f);
    float o0 = accx * inv + bias[c];
    float o1 = accy * inv + bias[c + 1];
    if (RELU) { o0 = fmaxf(o0, 0.f); o1 = fmaxf(o1, 0.f); }
    float2 o; o.x = o0; o.y = o1;
    *(float2*)&out[(size_t)n * 128 + c] = o;
}

// ---------------- launch ----------------

extern "C" void kernel_launch(void* const* d_in, const int* in_sizes, int n_in,
                              void* d_out, int out_size, void* d_ws, size_t ws_size,
                              hipStream_t stream) {
    const float* x   = (const float*)d_in[0];
    const int*   ei  = (const int*)d_in[1];
    const float* W1  = (const float*)d_in[2];
    const float* as1 = (const float*)d_in[3];
    const float* ad1 = (const float*)d_in[4];
    const float* b1  = (const float*)d_in[5];
    const float* W2  = (const float*)d_in[6];
    const float* as2 = (const float*)d_in[7];
    const float* ad2 = (const float*)d_in[8];
    const float* b2  = (const float*)d_in[9];
    const float* W3  = (const float*)d_in[10];
    const float* as3 = (const float*)d_in[11];
    const float* ad3 = (const float*)d_in[12];
    const float* b3  = (const float*)d_in[13];

    const int N = in_sizes[0] / 128;
    const int E = in_sizes[1] / 2;
    const int NB = (N + 255) / 256;

    char* w = (char*)d_ws;
    size_t woff = 0;
    auto alloc = [&](size_t bytes) -> void* {
        void* p = w + woff;
        woff = (woff + bytes + 255) & ~(size_t)255;
        return p;
    };
    int*      deg    = (int*)alloc((size_t)(N + 1) * 4);
    int*      offs   = (int*)alloc((size_t)(N + 1) * 4);
    int*      cursor = (int*)alloc((size_t)(N + 1) * 4);
    int*      bsum   = (int*)alloc((size_t)NB * 4);
    int*      srcs   = (int*)alloc((size_t)(E + N) * 4);
    float*    asb    = (float*)alloc((size_t)N * 4 * 4);
    float*    adb    = (float*)alloc((size_t)N * 4 * 4);
    unsigned* asMax  = (unsigned*)alloc((size_t)N * 4 * 4);
    unsigned short* hb = (unsigned short*)alloc((size_t)N * 128 * 2);
    float* outf = (float*)d_out;

    // CSR build (once)
    deg_init<<<(N + 255) / 256, 256, 0, stream>>>(deg, N);
    deg_count<<<(E + 255) / 256, 256, 0, stream>>>(ei, E, deg);
    scan_partial<<<NB, 256, 0, stream>>>(deg, N, bsum);
    scan_bsums<<<1, 256, 0, stream>>>(bsum, NB);
    scan_final<<<NB, 256, 0, stream>>>(deg, bsum, N, offs, cursor);
    scatter_edges<<<(E + N + 255) / 256, 256, 0, stream>>>(ei, E, N, cursor, srcs);

    const int gb = (N + 31) / 32;
    const int ga = (N + 3) / 4;           // aggregate: 4 waves/block, wave per node

    // Layer 1
    gemm_fused<4><<<gb, 256, 0, stream>>>(x, W1, as1, ad1, hb, asb, adb, asMax, N);
    edge_max<4><<<(E * 4 + 255) / 256, 256, 0, stream>>>(ei, E, asb, asMax);
    aggregate4<4, true><<<ga, 256, 0, stream>>>(hb, offs, srcs, asb, adb, asMax, b1, outf, N);

    // Layer 2
    gemm_fused<4><<<gb, 256, 0, stream>>>(outf, W2, as2, ad2, hb, asb, adb, asMax, N);
    edge_max<4><<<(E * 4 + 255) / 256, 256, 0, stream>>>(ei, E, asb, asMax);
    aggregate4<4, true><<<ga, 256, 0, stream>>>(hb, offs, srcs, asb, adb, asMax, b2, outf, N);

    // Layer 3 (H=1, no relu)
    gemm_fused<1><<<gb, 256, 0, stream>>>(outf, W3, as3, ad3, hb, asb, adb, asMax, N);
    edge_max<1><<<(E + 255) / 256, 256, 0, stream>>>(ei, E, asb, asMax);
    aggregate4<1, false><<<ga, 256, 0, stream>>>(hb, offs, srcs, asb, adb, asMax, b3, outf, N);
}

// Round 4
// 333.503 us; speedup vs baseline: 2.2248x; 1.3466x over previous
//
#include <hip/hip_runtime.h>
#include <hip/hip_bf16.h>
#include <math.h>

#define NPART 8

__device__ __forceinline__ float lrelu(float v) { return v > 0.f ? v : 0.2f * v; }

// monotone float <-> uint encoding for atomicMax on signed floats
__device__ __forceinline__ unsigned fenc(float f) {
    unsigned u = __float_as_uint(f);
    return (u & 0x80000000u) ? ~u : (u | 0x80000000u);
}
__device__ __forceinline__ float fdec(unsigned u) {
    return __uint_as_float((u & 0x80000000u) ? (u & 0x7FFFFFFFu) : ~u);
}
__device__ __forceinline__ unsigned short f2bf(float f) {
    union { __hip_bfloat16 b; unsigned short u; } cv;
    cv.b = __float2bfloat16(f);
    return cv.u;
}

// ---------------- CSR build (sort edges by dst), XCD-partitioned ----------------

__global__ void deg_init(int* deg, int N, unsigned* gmax) {
    int i = blockIdx.x * blockDim.x + threadIdx.x;
    if (i < N) deg[i] = 1;                    // self-loop
    if (i < 12) gmax[i] = fenc(-1e30f);       // per-layer per-head global max seeds
}

__global__ void deg_count_part(const int* __restrict__ ei, int E, int N, int* deg, int pn) {
    int part = blockIdx.x & (NPART - 1);
    int nb = gridDim.x >> 3;
    int chunk = blockIdx.x >> 3;
    int stride = nb * blockDim.x;
    int lo = part * pn, hi = min(lo + pn, N);
    for (int i = chunk * blockDim.x + threadIdx.x; i < E; i += stride) {
        int d = ei[E + i];
        if (d >= lo && d < hi) atomicAdd(&deg[d], 1);
    }
}

__global__ void scan_partial(const int* __restrict__ deg, int N, int* bsum) {
    __shared__ int sm[256];
    int t = threadIdx.x;
    int i = blockIdx.x * 256 + t;
    int v = (i < N) ? deg[i] : 0;
    sm[t] = v; __syncthreads();
    for (int o = 1; o < 256; o <<= 1) {
        int u = (t >= o) ? sm[t - o] : 0;
        __syncthreads();
        sm[t] += u;
        __syncthreads();
    }
    if (t == 255) bsum[blockIdx.x] = sm[255];
}

__global__ void scan_bsums(int* bsum, int nb) {
    __shared__ int sm[256];
    int t = threadIdx.x;
    int v = (t < nb) ? bsum[t] : 0;
    sm[t] = v; __syncthreads();
    for (int o = 1; o < 256; o <<= 1) {
        int u = (t >= o) ? sm[t - o] : 0;
        __syncthreads();
        sm[t] += u;
        __syncthreads();
    }
    if (t < nb) bsum[t] = sm[t] - v;          // exclusive
}

__global__ void scan_final(const int* __restrict__ deg, const int* __restrict__ bsum,
                           int N, int* offs, int* cursor) {
    __shared__ int sm[256];
    int t = threadIdx.x;
    int i = blockIdx.x * 256 + t;
    int v = (i < N) ? deg[i] : 0;
    sm[t] = v; __syncthreads();
    for (int o = 1; o < 256; o <<= 1) {
        int u = (t >= o) ? sm[t - o] : 0;
        __syncthreads();
        sm[t] += u;
        __syncthreads();
    }
    int incl = sm[t] + bsum[blockIdx.x];
    if (i < N) { offs[i + 1] = incl; cursor[i] = incl - v; }
    if (i == 0) offs[0] = 0;
}

__global__ void scatter_part(const int* __restrict__ ei, int E, int N,
                             int* cursor, int* srcs, int pn) {
    int part = blockIdx.x & (NPART - 1);
    int nb = gridDim.x >> 3;
    int chunk = blockIdx.x >> 3;
    int stride = nb * blockDim.x;
    int lo = part * pn, hi = min(lo + pn, N);
    for (int i = chunk * blockDim.x + threadIdx.x; i < E; i += stride) {
        int d = ei[E + i];
        if (d >= lo && d < hi) {
            int pos = atomicAdd(&cursor[d], 1);
            srcs[pos] = ei[i];
        }
    }
    for (int i = chunk * blockDim.x + threadIdx.x + lo; i < hi; i += stride) {
        int pos = atomicAdd(&cursor[i], 1);
        srcs[pos] = i;                         // self-loop
    }
}

// ------- GEMM + fused node logits: h=X@W (bf16 out), as/ad per (node,head) -------

template <int H>
__global__ __launch_bounds__(256, 2) void gemm_fused(const float* __restrict__ X,
                                                     const float* __restrict__ W,
                                                     const float* __restrict__ a_s,
                                                     const float* __restrict__ a_d,
                                                     unsigned short* __restrict__ hb,
                                                     float* __restrict__ asb,
                                                     float* __restrict__ adb,
                                                     int N) {
    __shared__ float wl[128 * 128];   // [k][c]
    __shared__ float xt[128 * 32];    // [k][r]
    int t = threadIdx.x;
    {
        const float4* W4 = (const float4*)W;
        float4* wl4 = (float4*)wl;
#pragma unroll
        for (int i = 0; i < 16; i++) wl4[t + 256 * i] = W4[t + 256 * i];
    }
    int row0 = blockIdx.x * 32;
    {
        int r = t & 31, kc = t >> 5;
        int row = row0 + r;
        bool ok = row < N;
        const float4* src = (const float4*)(X + (size_t)row * 128 + kc * 16);
        float4 z; z.x = z.y = z.z = z.w = 0.f;
#pragma unroll
        for (int q = 0; q < 4; q++) {
            float4 v = ok ? src[q] : z;
            int k = kc * 16 + q * 4;
            xt[(k + 0) * 32 + r] = v.x;
            xt[(k + 1) * 32 + r] = v.y;
            xt[(k + 2) * 32 + r] = v.z;
            xt[(k + 3) * 32 + r] = v.w;
        }
    }
    __syncthreads();
    int cg = t & 31, rg = t >> 5;
    float acc[4][4];
#pragma unroll
    for (int i = 0; i < 4; i++)
#pragma unroll
        for (int j = 0; j < 4; j++) acc[i][j] = 0.f;
    const float4* xt4  = (const float4*)xt;
    const float4* wl4r = (const float4*)wl;
#pragma unroll 8
    for (int k = 0; k < 128; k++) {
        float4 xv = xt4[k * 8 + rg];
        float4 wv = wl4r[k * 32 + cg];
        acc[0][0] += xv.x * wv.x; acc[0][1] += xv.x * wv.y; acc[0][2] += xv.x * wv.z; acc[0][3] += xv.x * wv.w;
        acc[1][0] += xv.y * wv.x; acc[1][1] += xv.y * wv.y; acc[1][2] += xv.y * wv.z; acc[1][3] += xv.y * wv.w;
        acc[2][0] += xv.z * wv.x; acc[2][1] += xv.z * wv.y; acc[2][2] += xv.z * wv.z; acc[2][3] += xv.z * wv.w;
        acc[3][0] += xv.w * wv.x; acc[3][1] += xv.w * wv.y; acc[3][2] += xv.w * wv.z; acc[3][3] += xv.w * wv.w;
    }
    // write bf16 h
#pragma unroll
    for (int i = 0; i < 4; i++) {
        int row = row0 + rg * 4 + i;
        if (row < N) {
            ushort4 o;
            o.x = f2bf(acc[i][0]); o.y = f2bf(acc[i][1]);
            o.z = f2bf(acc[i][2]); o.w = f2bf(acc[i][3]);
            *(ushort4*)&hb[(size_t)row * 128 + cg * 4] = o;
        }
    }
    // fused per-(row,head) logits
    constexpr int C = 128 / H;
    int head = (H == 4) ? (cg >> 3) : 0;
    int cidx = (H == 4) ? ((cg & 7) * 4) : (cg * 4);
    float4 as4 = *(const float4*)&a_s[head * C + cidx];
    float4 ad4 = *(const float4*)&a_d[head * C + cidx];
    float ps[4], pd[4];
#pragma unroll
    for (int i = 0; i < 4; i++) {
        ps[i] = acc[i][0] * as4.x + acc[i][1] * as4.y + acc[i][2] * as4.z + acc[i][3] * as4.w;
        pd[i] = acc[i][0] * ad4.x + acc[i][1] * ad4.y + acc[i][2] * ad4.z + acc[i][3] * ad4.w;
    }
    constexpr int RED = (H == 4) ? 8 : 32;
    for (int o = 1; o < RED; o <<= 1) {
#pragma unroll
        for (int i = 0; i < 4; i++) {
            ps[i] += __shfl_xor(ps[i], o);
            pd[i] += __shfl_xor(pd[i], o);
        }
    }
    if ((t & (RED - 1)) == 0) {
#pragma unroll
        for (int i = 0; i < 4; i++) {
            int row = row0 + rg * 4 + i;
            if (row < N) {
                asb[(size_t)row * H + head] = ps[i];
                adb[(size_t)row * H + head] = pd[i];
            }
        }
    }
}

// ------- per-head global max of asb (upper bound for softmax stabilizer) -------

template <int H>
__global__ void head_max(const float* __restrict__ asb, int NH, unsigned* gmax) {
    float m = -1e30f;
    int stride = gridDim.x * blockDim.x;       // multiple of H (blockDim=256)
    for (int i = blockIdx.x * blockDim.x + threadIdx.x; i < NH; i += stride)
        m = fmaxf(m, asb[i]);
    for (int o = H; o < 64; o <<= 1) m = fmaxf(m, __shfl_xor(m, o));
    if ((threadIdx.x & 63) < H) atomicMax(&gmax[threadIdx.x & 63], fenc(m));
}

// ------- aggregation: one wave per dst node, inline softmax, bf16 h gather, MLP-8 -------

template <int H, bool RELU>
__global__ __launch_bounds__(256) void aggregate5(const unsigned short* __restrict__ hb,
                                                  const int* __restrict__ offs,
                                                  const int* __restrict__ srcs,
                                                  const float* __restrict__ asb,
                                                  const float* __restrict__ adb,
                                                  const unsigned* __restrict__ gmax,
                                                  const float* __restrict__ bias,
                                                  float* __restrict__ out, int N) {
    int n = (blockIdx.x * 256 + threadIdx.x) >> 6;   // wave id = node
    if (n >= N) return;
    int lane = threadIdx.x & 63;
    int c = lane * 2;                                 // 2 channels per lane
    int ht = (H == 4) ? (lane >> 4) : 0;
    float adn = adb[(size_t)n * H + ht];
    float m = lrelu(fdec(gmax[ht]) + adn);            // global-bound stabilizer
    int beg = offs[n], end = offs[n + 1];
    float accx = 0.f, accy = 0.f, den = 0.f;
    int s0 = srcs[beg];
    for (int j = beg; j < end; j += 8) {
        int s[8]; unsigned u[8]; float e[8]; bool ok[8];
#pragma unroll
        for (int q = 0; q < 8; q++) {
            ok[q] = (j + q) < end;
            s[q] = ok[q] ? srcs[j + q] : s0;
        }
#pragma unroll
        for (int q = 0; q < 8; q++)
            u[q] = *(const unsigned*)&hb[(size_t)s[q] * 128 + c];
#pragma unroll
        for (int q = 0; q < 8; q++)
            e[q] = asb[(size_t)s[q] * H + ht];
#pragma unroll
        for (int q = 0; q < 8; q++) {
            float p = __expf(lrelu(e[q] + adn) - m);
            p = ok[q] ? p : 0.f;
            accx += p * __uint_as_float(u[q] << 16);
            accy += p * __uint_as_float(u[q] & 0xFFFF0000u);
            den += p;
        }
    }
    float inv = 1.f / (den + 1e-16f);
    float o0 = accx * inv + bias[c];
    float o1 = accy * inv + bias[c + 1];
    if (RELU) { o0 = fmaxf(o0, 0.f); o1 = fmaxf(o1, 0.f); }
    float2 o; o.x = o0; o.y = o1;
    *(float2*)&out[(size_t)n * 128 + c] = o;
}

// ---------------- launch ----------------

extern "C" void kernel_launch(void* const* d_in, const int* in_sizes, int n_in,
                              void* d_out, int out_size, void* d_ws, size_t ws_size,
                              hipStream_t stream) {
    const float* x   = (const float*)d_in[0];
    const int*   ei  = (const int*)d_in[1];
    const float* W1  = (const float*)d_in[2];
    const float* as1 = (const float*)d_in[3];
    const float* ad1 = (const float*)d_in[4];
    const float* b1  = (const float*)d_in[5];
    const float* W2  = (const float*)d_in[6];
    const float* as2 = (const float*)d_in[7];
    const float* ad2 = (const float*)d_in[8];
    const float* b2  = (const float*)d_in[9];
    const float* W3  = (const float*)d_in[10];
    const float* as3 = (const float*)d_in[11];
    const float* ad3 = (const float*)d_in[12];
    const float* b3  = (const float*)d_in[13];

    const int N = in_sizes[0] / 128;
    const int E = in_sizes[1] / 2;
    const int NB = (N + 255) / 256;
    const int PN = (N + NPART - 1) / NPART;

    char* w = (char*)d_ws;
    size_t woff = 0;
    auto alloc = [&](size_t bytes) -> void* {
        void* p = w + woff;
        woff = (woff + bytes + 255) & ~(size_t)255;
        return p;
    };
    int*      deg    = (int*)alloc((size_t)(N + 1) * 4);
    int*      offs   = (int*)alloc((size_t)(N + 1) * 4);
    int*      cursor = (int*)alloc((size_t)(N + 1) * 4);
    int*      bsum   = (int*)alloc((size_t)NB * 4);
    int*      srcs   = (int*)alloc((size_t)(E + N) * 4);
    float*    asb    = (float*)alloc((size_t)N * 4 * 4);
    float*    adb    = (float*)alloc((size_t)N * 4 * 4);
    unsigned* gmax   = (unsigned*)alloc(16 * 4);
    unsigned short* hb = (unsigned short*)alloc((size_t)N * 128 * 2);
    float* outf = (float*)d_out;

    // CSR build (XCD-partitioned scatter)
    deg_init<<<(N + 255) / 256, 256, 0, stream>>>(deg, N, gmax);
    deg_count_part<<<2048, 256, 0, stream>>>(ei, E, N, deg, PN);
    scan_partial<<<NB, 256, 0, stream>>>(deg, N, bsum);
    scan_bsums<<<1, 256, 0, stream>>>(bsum, NB);
    scan_final<<<NB, 256, 0, stream>>>(deg, bsum, N, offs, cursor);
    scatter_part<<<2048, 256, 0, stream>>>(ei, E, N, cursor, srcs, PN);

    const int gb = (N + 31) / 32;
    const int ga = (N + 3) / 4;           // aggregate: 4 waves/block, wave per node

    // Layer 1
    gemm_fused<4><<<gb, 256, 0, stream>>>(x, W1, as1, ad1, hb, asb, adb, N);
    head_max<4><<<104, 256, 0, stream>>>(asb, N * 4, gmax + 0);
    aggregate5<4, true><<<ga, 256, 0, stream>>>(hb, offs, srcs, asb, adb, gmax + 0, b1, outf, N);

    // Layer 2
    gemm_fused<4><<<gb, 256, 0, stream>>>(outf, W2, as2, ad2, hb, asb, adb, N);
    head_max<4><<<104, 256, 0, stream>>>(asb, N * 4, gmax + 4);
    aggregate5<4, true><<<ga, 256, 0, stream>>>(hb, offs, srcs, asb, adb, gmax + 4, b2, outf, N);

    // Layer 3 (H=1, no relu)
    gemm_fused<1><<<gb, 256, 0, stream>>>(outf, W3, as3, ad3, hb, asb, adb, N);
    head_max<1><<<104, 256, 0, stream>>>(asb, N, gmax + 8);
    aggregate5<1, false><<<ga, 256, 0, stream>>>(hb, offs, srcs, asb, adb, gmax + 8, b3, outf, N);
}